// Round 15
// baseline (115.186 us; speedup 1.0000x reference)
//
#include <hip/hip_runtime.h>

#define DIN 128
#define DOUT 64
#define NEG_SLOPE 0.2f
#define ALPHA 0.5f
#define NBUK 512    // coarse buckets: bucket = seg >> 8, covers 2n = 100000 segments
#define EPB  4096   // edges per block in binning passes (196 blocks)
#define BCCAP 6144  // buildcsr LDS staging cache (entries)

typedef __attribute__((ext_vector_type(8))) short bf16x8;
typedef __attribute__((ext_vector_type(4))) float f32x4;

__device__ __forceinline__ float lrelu(float x) { return x > 0.0f ? x : NEG_SLOPE * x; }

__device__ __forceinline__ unsigned short f2bf(float f) {
    unsigned u = __float_as_uint(f);
    unsigned r = (u + 0x7fffu + ((u >> 16) & 1u)) >> 16;
    return (unsigned short)r;
}
__device__ __forceinline__ float bf2f(unsigned short h) {
    return __uint_as_float((unsigned)h << 16);
}
__device__ __forceinline__ float readlane_f(float v, int l) {
    return __int_as_float(__builtin_amdgcn_readlane(__float_as_int(v), l));
}

// ================= device-phase bodies (shared by fused kernels) =============

// wfrag: bf16 (hi only). wf[(mat*16 + kk*4 + t)*512 + l*8 + j], 32 KB total.
__device__ __forceinline__ void dev_wfrag(
    const float* __restrict__ W1, const float* __restrict__ W2,
    unsigned short* __restrict__ wf, int blk, int tid)
{
    int combo = blk * 4 + (tid >> 6);     // [0,32)
    int mat = combo >> 4;
    int kk = (combo >> 2) & 3;
    int t = combo & 3;
    int l = tid & 63;
    int g = l >> 4, c = l & 15;
    const float* W = mat ? W2 : W1;
    #pragma unroll
    for (int j = 0; j < 8; ++j) {
        float w = W[(kk * 32 + g * 8 + j) * DOUT + t * 16 + c];
        wf[(size_t)((mat * 16 + kk * 4 + t) * 512) + l * 8 + j] = f2bf(w);
    }
}

__device__ __forceinline__ void dev_binhist(
    const int* __restrict__ src, const int* __restrict__ dst,
    int* __restrict__ hist, int e, int n, int nblk, int blk, int tid, int* cnt)
{
    for (int b = tid; b < NBUK; b += 256) cnt[b] = 0;
    __syncthreads();
    int base = blk * EPB;
    for (int k = 0; k < EPB / 256; ++k) {
        int t = base + k * 256 + tid;
        if (t < e) {
            int s = src[t], d = dst[t];
            atomicAdd(&cnt[d >> 8], 1);
            atomicAdd(&cnt[(n + s) >> 8], 1);
        }
    }
    __syncthreads();
    for (int b = tid; b < NBUK; b += 256)
        hist[(size_t)b * nblk + blk] = cnt[b];   // bucket-major
}

__device__ __forceinline__ void dev_scan_part(
    const int* __restrict__ deg, int* __restrict__ part, int L, int blk, int tid, int* sm)
{
    int base = blk * 1024 + tid * 4;
    int s = 0;
    #pragma unroll
    for (int k = 0; k < 4; ++k) { int i = base + k; if (i < L) s += deg[i]; }
    sm[tid] = s; __syncthreads();
    for (int o = 128; o; o >>= 1) { if (tid < o) sm[tid] += sm[tid + o]; __syncthreads(); }
    if (tid == 0) part[blk] = sm[0];
}

// 256-thread scan of ntile (<=256) partial sums; also writes hscan[L] = total
__device__ __forceinline__ void dev_scan_mid(
    int* __restrict__ part, int nb, int* __restrict__ hscan, int L, int total,
    int tid, int* sm)
{
    int v = (tid < nb) ? part[tid] : 0;
    sm[tid] = v; __syncthreads();
    for (int o = 1; o < 256; o <<= 1) {
        int u = (tid >= o) ? sm[tid - o] : 0;
        __syncthreads();
        sm[tid] += u;
        __syncthreads();
    }
    if (tid < nb) part[tid] = sm[tid] - v;   // exclusive
    if (tid == 0) hscan[L] = total;
}

__device__ __forceinline__ void dev_scan_apply(
    const int* __restrict__ deg, const int* __restrict__ part,
    int* __restrict__ hscan, int L, int blk, int tid, int* sm)
{
    int base = blk * 1024 + tid * 4;
    int d[4]; int s = 0;
    #pragma unroll
    for (int k = 0; k < 4; ++k) { int i = base + k; d[k] = (i < L) ? deg[i] : 0; s += d[k]; }
    sm[tid] = s; __syncthreads();
    for (int o = 1; o < 256; o <<= 1) {
        int u = (tid >= o) ? sm[tid - o] : 0;
        __syncthreads();
        sm[tid] += u;
        __syncthreads();
    }
    int run = part[blk] + sm[tid] - s;
    #pragma unroll
    for (int k = 0; k < 4; ++k) {
        int i = base + k;
        if (i < L) { hscan[i] = run; run += d[k]; }
    }
}

__device__ __forceinline__ void dev_binscatter(
    const int* __restrict__ src, const int* __restrict__ dst,
    const int* __restrict__ hscan, unsigned* __restrict__ staging,
    int e, int n, int nblk, int blk, int tid, int* cur)
{
    for (int b = tid; b < NBUK; b += 256)
        cur[b] = hscan[(size_t)b * nblk + blk];
    __syncthreads();
    int base = blk * EPB;
    for (int k = 0; k < EPB / 256; ++k) {
        int t = base + k * 256 + tid;
        if (t < e) {
            int s = src[t], d = dst[t];
            int pF = atomicAdd(&cur[d >> 8], 1);
            staging[pF] = ((unsigned)(d & 255) << 16) | (unsigned)s;
            int segR = n + s;
            int pR = atomicAdd(&cur[segR >> 8], 1);
            staging[pR] = ((unsigned)(segR & 255) << 16) | (unsigned)d;
        }
    }
}

// proj via MFMA, plain bf16 (xw stored bf16 anyway; input-rounding error ~1e-4
// vs 1.17e-2 threshold). 2 tiles (32 nodes) per wave; projblk in [0,391).
__device__ __forceinline__ void dev_proj(
    const float* __restrict__ x, const unsigned short* __restrict__ wf,
    const float* __restrict__ as1, const float* __restrict__ ad1,
    const float* __restrict__ as2, const float* __restrict__ ad2,
    unsigned short* __restrict__ xw1, unsigned short* __restrict__ xw2,
    float* __restrict__ s1, float* __restrict__ d1,
    float* __restrict__ s2, float* __restrict__ d2, int n, int projblk, int tid)
{
    int ntiles = (n + 15) >> 4;
    int tbase = projblk * 8 + (tid >> 6) * 2;
    if (tbase >= ntiles) return;
    int l = tid & 63;
    int g = l >> 4, c = l & 15;

    // A fragments for 2 tiles (clamped rows; stores guarded)
    bf16x8 ah[2][4];
    #pragma unroll
    for (int u = 0; u < 2; ++u) {
        int arow = (tbase + u) * 16 + c;
        if (arow >= n) arow = n - 1;
        const float* xr = x + (size_t)arow * DIN + g * 8;
        #pragma unroll
        for (int kk = 0; kk < 4; ++kk) {
            float4 v0 = *(const float4*)(xr + kk * 32);
            float4 v1 = *(const float4*)(xr + kk * 32 + 4);
            float xv[8] = {v0.x, v0.y, v0.z, v0.w, v1.x, v1.y, v1.z, v1.w};
            #pragma unroll
            for (int j = 0; j < 8; ++j) ah[u][kk][j] = (short)f2bf(xv[j]);
        }
    }

    float vs1[2][4] = {}, vd1[2][4] = {}, vs2[2][4] = {}, vd2[2][4] = {};
    const bf16x8* wfv = (const bf16x8*)wf;   // [(mat*16 + kk*4 + t)*64 + lane]

    #pragma unroll
    for (int t = 0; t < 4; ++t) {
        f32x4 C1[2] = {{0.f,0.f,0.f,0.f},{0.f,0.f,0.f,0.f}};
        f32x4 C2[2] = {{0.f,0.f,0.f,0.f},{0.f,0.f,0.f,0.f}};
        #pragma unroll
        for (int kk = 0; kk < 4; ++kk) {
            bf16x8 bh1 = wfv[(size_t)((0 * 16 + kk * 4 + t) * 64) + l];
            bf16x8 bh2 = wfv[(size_t)((1 * 16 + kk * 4 + t) * 64) + l];
            #pragma unroll
            for (int u = 0; u < 2; ++u) {
                C1[u] = __builtin_amdgcn_mfma_f32_16x16x32_bf16(ah[u][kk], bh1, C1[u], 0, 0, 0);
                C2[u] = __builtin_amdgcn_mfma_f32_16x16x32_bf16(ah[u][kk], bh2, C2[u], 0, 0, 0);
            }
        }
        float a1v = as1[t * 16 + c], a2v = ad1[t * 16 + c];
        float a3v = as2[t * 16 + c], a4v = ad2[t * 16 + c];
        #pragma unroll
        for (int u = 0; u < 2; ++u) {
            #pragma unroll
            for (int r = 0; r < 4; ++r) {
                vs1[u][r] = fmaf(C1[u][r], a1v, vs1[u][r]);
                vd1[u][r] = fmaf(C1[u][r], a2v, vd1[u][r]);
                vs2[u][r] = fmaf(C2[u][r], a3v, vs2[u][r]);
                vd2[u][r] = fmaf(C2[u][r], a4v, vd2[u][r]);
                int node = (tbase + u) * 16 + g * 4 + r;
                if (node < n) {
                    xw1[(size_t)node * DOUT + t * 16 + c] = f2bf(C1[u][r]);
                    xw2[(size_t)node * DOUT + t * 16 + c] = f2bf(C2[u][r]);
                }
            }
        }
    }
    #pragma unroll
    for (int off = 1; off < 16; off <<= 1) {
        #pragma unroll
        for (int u = 0; u < 2; ++u) {
            #pragma unroll
            for (int r = 0; r < 4; ++r) {
                vs1[u][r] += __shfl_xor(vs1[u][r], off);
                vd1[u][r] += __shfl_xor(vd1[u][r], off);
                vs2[u][r] += __shfl_xor(vs2[u][r], off);
                vd2[u][r] += __shfl_xor(vd2[u][r], off);
            }
        }
    }
    if (c == 0) {
        #pragma unroll
        for (int u = 0; u < 2; ++u) {
            #pragma unroll
            for (int r = 0; r < 4; ++r) {
                int node = (tbase + u) * 16 + g * 4 + r;
                if (node < n) {
                    s1[node] = vs1[u][r]; d1[node] = vd1[u][r];
                    s2[node] = vs2[u][r]; d2[node] = vd2[u][r];
                }
            }
        }
    }
}

// ================= fused launches =============

// F1: wfrag (blk<8) ∪ binhist (blk-8)
__global__ __launch_bounds__(256) void fused1_kernel(
    const float* __restrict__ W1, const float* __restrict__ W2,
    unsigned short* __restrict__ wf,
    const int* __restrict__ src, const int* __restrict__ dst,
    int* __restrict__ hist, int e, int n, int nblk)
{
    __shared__ int smem[NBUK];
    int blk = blockIdx.x, tid = threadIdx.x;
    if (blk < 8) dev_wfrag(W1, W2, wf, blk, tid);
    else dev_binhist(src, dst, hist, e, n, nblk, blk - 8, tid, smem);
}

// F2: scan_part (blk<ntile) ∪ proj chunk 0
__global__ __launch_bounds__(256) void fused2_kernel(
    const int* __restrict__ hist, int* __restrict__ part, int L, int ntile,
    const float* __restrict__ x, const unsigned short* __restrict__ wf,
    const float* __restrict__ as1, const float* __restrict__ ad1,
    const float* __restrict__ as2, const float* __restrict__ ad2,
    unsigned short* __restrict__ xw1, unsigned short* __restrict__ xw2,
    float* __restrict__ s1, float* __restrict__ d1,
    float* __restrict__ s2, float* __restrict__ d2, int n, int proj0)
{
    __shared__ int smem[256];
    int blk = blockIdx.x, tid = threadIdx.x;
    if (blk < ntile) dev_scan_part(hist, part, L, blk, tid, smem);
    else dev_proj(x, wf, as1, ad1, as2, ad2, xw1, xw2, s1, d1, s2, d2, n,
                  proj0 + blk - ntile, tid);
}

// F3: scan_mid (blk==0) ∪ proj chunk 1
__global__ __launch_bounds__(256) void fused3_kernel(
    int* __restrict__ part, int ntile, int* __restrict__ hscan, int L, int total,
    const float* __restrict__ x, const unsigned short* __restrict__ wf,
    const float* __restrict__ as1, const float* __restrict__ ad1,
    const float* __restrict__ as2, const float* __restrict__ ad2,
    unsigned short* __restrict__ xw1, unsigned short* __restrict__ xw2,
    float* __restrict__ s1, float* __restrict__ d1,
    float* __restrict__ s2, float* __restrict__ d2, int n, int proj0)
{
    __shared__ int smem[256];
    int blk = blockIdx.x, tid = threadIdx.x;
    if (blk == 0) dev_scan_mid(part, ntile, hscan, L, total, tid, smem);
    else dev_proj(x, wf, as1, ad1, as2, ad2, xw1, xw2, s1, d1, s2, d2, n,
                  proj0 + blk - 1, tid);
}

// F4: scan_apply (blk<ntile) ∪ proj chunk 2
__global__ __launch_bounds__(256) void fused4_kernel(
    const int* __restrict__ hist, const int* __restrict__ part,
    int* __restrict__ hscan, int L, int ntile,
    const float* __restrict__ x, const unsigned short* __restrict__ wf,
    const float* __restrict__ as1, const float* __restrict__ ad1,
    const float* __restrict__ as2, const float* __restrict__ ad2,
    unsigned short* __restrict__ xw1, unsigned short* __restrict__ xw2,
    float* __restrict__ s1, float* __restrict__ d1,
    float* __restrict__ s2, float* __restrict__ d2, int n, int proj0)
{
    __shared__ int smem[256];
    int blk = blockIdx.x, tid = threadIdx.x;
    if (blk < ntile) dev_scan_apply(hist, part, hscan, L, blk, tid, smem);
    else dev_proj(x, wf, as1, ad1, as2, ad2, xw1, xw2, s1, d1, s2, d2, n,
                  proj0 + blk - ntile, tid);
}

// F5: binscatter (blk<nblk) ∪ proj chunk 3
__global__ __launch_bounds__(256) void fused5_kernel(
    const int* __restrict__ src, const int* __restrict__ dst,
    const int* __restrict__ hscan, unsigned* __restrict__ staging,
    int e, int nblk,
    const float* __restrict__ x, const unsigned short* __restrict__ wf,
    const float* __restrict__ as1, const float* __restrict__ ad1,
    const float* __restrict__ as2, const float* __restrict__ ad2,
    unsigned short* __restrict__ xw1, unsigned short* __restrict__ xw2,
    float* __restrict__ s1, float* __restrict__ d1,
    float* __restrict__ s2, float* __restrict__ d2, int n, int proj0)
{
    __shared__ int smem[NBUK];
    int blk = blockIdx.x, tid = threadIdx.x;
    if (blk < nblk) dev_binscatter(src, dst, hscan, staging, e, n, nblk, blk, tid, smem);
    else dev_proj(x, wf, as1, ad1, as2, ad2, xw1, xw2, s1, d1, s2, d2, n,
                  proj0 + blk - nblk, tid);
}

// ---------------- pass B: one block per bucket (256 segments) -> offs + csr.
__global__ __launch_bounds__(256) void buildcsr_kernel(
    const int* __restrict__ hscan, const unsigned* __restrict__ staging,
    int* __restrict__ csr, int* __restrict__ offs,
    int n2, int e2, int nblk)
{
    __shared__ int segcnt[256];
    __shared__ int segoff[256];
    __shared__ unsigned cache[BCCAP];
    int b = blockIdx.x, tid = threadIdx.x;
    int lo = hscan[(size_t)b * nblk];
    int hi = hscan[(size_t)(b + 1) * nblk];
    int span = hi - lo;
    segcnt[tid] = 0;
    __syncthreads();
    if (span <= BCCAP) {
        for (int k = tid; k < span; k += 256) {
            unsigned st = staging[lo + k];
            cache[k] = st;
            atomicAdd(&segcnt[st >> 16], 1);
        }
    } else {
        for (int idx = lo + tid; idx < hi; idx += 256)
            atomicAdd(&segcnt[staging[idx] >> 16], 1);
    }
    __syncthreads();
    if (tid < 64) {
        int a0 = segcnt[4 * tid], a1 = segcnt[4 * tid + 1];
        int a2 = segcnt[4 * tid + 2], a3 = segcnt[4 * tid + 3];
        int s = a0 + a1 + a2 + a3;
        int inc = s;
        #pragma unroll
        for (int off = 1; off < 64; off <<= 1) {
            int u = __shfl_up(inc, off);
            if (tid >= off) inc += u;
        }
        int excl = inc - s;
        segoff[4 * tid] = excl;
        segoff[4 * tid + 1] = excl + a0;
        segoff[4 * tid + 2] = excl + a0 + a1;
        segoff[4 * tid + 3] = excl + a0 + a1 + a2;
    }
    __syncthreads();
    {
        int seg = (b << 8) + tid;
        if (seg < n2) offs[seg] = lo + segoff[tid];
        segcnt[tid] = segoff[tid];   // running cursors
    }
    if (b == gridDim.x - 1 && tid == 0) offs[n2] = e2;
    __syncthreads();
    if (span <= BCCAP) {
        for (int k = tid; k < span; k += 256) {
            unsigned st = cache[k];
            int pos = atomicAdd(&segcnt[st >> 16], 1);
            csr[lo + pos] = (int)(st & 0xFFFFu);
        }
    } else {
        for (int idx = lo + tid; idx < hi; idx += 256) {
            unsigned st = staging[idx];
            int pos = atomicAdd(&segcnt[st >> 16], 1);
            csr[lo + pos] = (int)(st & 0xFFFFu);
        }
    }
}

// ---------------- gather: ONE wave per node, both directions fused.
// No online max; denominators accumulated from the (wave-uniform) readlane'd
// p values inside the accumulate loop — no shuffle sum.
__global__ __launch_bounds__(256) void gather_kernel(
    const int* __restrict__ offs, const int* __restrict__ csr,
    const float* __restrict__ s1, const float* __restrict__ d1,
    const float* __restrict__ s2, const float* __restrict__ d2,
    const unsigned short* __restrict__ xw1, const unsigned short* __restrict__ xw2,
    const float* __restrict__ b1, const float* __restrict__ b2,
    float* __restrict__ out, int n)
{
    int i = (blockIdx.x * 256 + threadIdx.x) >> 6;
    int lane = threadIdx.x & 63;
    if (i >= n) return;

    float d1i = d1[i], d2i = d2[i];
    int cF = offs[i],     endF = offs[i + 1];
    int cR = offs[n + i], endR = offs[n + i + 1];

    float pSF = __expf(lrelu(s1[i] + d1i));
    float pSR = __expf(lrelu(s2[i] + d2i));
    float lF0 = pSF, lF1 = 0.f, lR0 = pSR, lR1 = 0.f;
    float aF0 = pSF * bf2f(xw1[(size_t)i * DOUT + lane]), aF1 = 0.f, aF2 = 0.f, aF3 = 0.f;
    float aR0 = pSR * bf2f(xw2[(size_t)i * DOUT + lane]), aR1 = 0.f, aR2 = 0.f, aR3 = 0.f;

    while (cF < endF || cR < endR) {
        int cntF = endF - cF; cntF = cntF < 0 ? 0 : (cntF > 64 ? 64 : cntF);
        int cntR = endR - cR; cntR = cntR < 0 ? 0 : (cntR > 64 ? 64 : cntR);

        int jF = 0, jR = 0;
        float pF = 0.0f, pR = 0.0f;
        if (lane < cntF) { jF = csr[cF + lane]; pF = __expf(lrelu(s1[jF] + d1i)); }
        if (lane < cntR) { jR = csr[cR + lane]; pR = __expf(lrelu(s2[jR] + d2i)); }

        int tmax = cntF > cntR ? cntF : cntR;
        int t = 0;
        for (; t + 4 <= tmax; t += 4) {
            float pF0 = readlane_f(pF, t),     pF1 = readlane_f(pF, t + 1);
            float pF2 = readlane_f(pF, t + 2), pF3 = readlane_f(pF, t + 3);
            int   jF0 = __builtin_amdgcn_readlane(jF, t);
            int   jF1 = __builtin_amdgcn_readlane(jF, t + 1);
            int   jF2 = __builtin_amdgcn_readlane(jF, t + 2);
            int   jF3 = __builtin_amdgcn_readlane(jF, t + 3);
            float pR0 = readlane_f(pR, t),     pR1 = readlane_f(pR, t + 1);
            float pR2 = readlane_f(pR, t + 2), pR3 = readlane_f(pR, t + 3);
            int   jR0 = __builtin_amdgcn_readlane(jR, t);
            int   jR1 = __builtin_amdgcn_readlane(jR, t + 1);
            int   jR2 = __builtin_amdgcn_readlane(jR, t + 2);
            int   jR3 = __builtin_amdgcn_readlane(jR, t + 3);
            lF0 += pF0 + pF1; lF1 += pF2 + pF3;
            lR0 += pR0 + pR1; lR1 += pR2 + pR3;
            aF0 = fmaf(pF0, bf2f(xw1[(size_t)jF0 * DOUT + lane]), aF0);
            aF1 = fmaf(pF1, bf2f(xw1[(size_t)jF1 * DOUT + lane]), aF1);
            aF2 = fmaf(pF2, bf2f(xw1[(size_t)jF2 * DOUT + lane]), aF2);
            aF3 = fmaf(pF3, bf2f(xw1[(size_t)jF3 * DOUT + lane]), aF3);
            aR0 = fmaf(pR0, bf2f(xw2[(size_t)jR0 * DOUT + lane]), aR0);
            aR1 = fmaf(pR1, bf2f(xw2[(size_t)jR1 * DOUT + lane]), aR1);
            aR2 = fmaf(pR2, bf2f(xw2[(size_t)jR2 * DOUT + lane]), aR2);
            aR3 = fmaf(pR3, bf2f(xw2[(size_t)jR3 * DOUT + lane]), aR3);
        }
        for (; t < tmax; ++t) {
            float pF0 = readlane_f(pF, t);
            int   jF0 = __builtin_amdgcn_readlane(jF, t);
            float pR0 = readlane_f(pR, t);
            int   jR0 = __builtin_amdgcn_readlane(jR, t);
            lF0 += pF0; lR0 += pR0;
            aF0 = fmaf(pF0, bf2f(xw1[(size_t)jF0 * DOUT + lane]), aF0);
            aR0 = fmaf(pR0, bf2f(xw2[(size_t)jR0 * DOUT + lane]), aR0);
        }
        cF += cntF;
        cR += cntR;
    }

    float lF = lF0 + lF1, lR = lR0 + lR1;
    float resF = ((aF0 + aF1) + (aF2 + aF3)) / (lF + 1e-16f);
    float resR = ((aR0 + aR1) + (aR2 + aR3)) / (lR + 1e-16f);
    out[(size_t)i * DOUT + lane] =
        (1.0f - ALPHA) * (resF + b1[lane]) + ALPHA * (resR + b2[lane]);
}

extern "C" void kernel_launch(void* const* d_in, const int* in_sizes, int n_in,
                              void* d_out, int out_size, void* d_ws, size_t ws_size,
                              hipStream_t stream) {
    const float* x   = (const float*)d_in[0];
    const int*   ei  = (const int*)d_in[1];
    const float* W1  = (const float*)d_in[2];
    const float* as1 = (const float*)d_in[3];
    const float* ad1 = (const float*)d_in[4];
    const float* b1  = (const float*)d_in[5];
    const float* W2  = (const float*)d_in[6];
    const float* as2 = (const float*)d_in[7];
    const float* ad2 = (const float*)d_in[8];
    const float* b2  = (const float*)d_in[9];
    float* out = (float*)d_out;

    int n = in_sizes[0] / DIN;   // 50000  (< 65536 for 16-bit staging pack)
    int e = in_sizes[1] / 2;     // 800000
    const int* src = ei;
    const int* dst = ei + e;
    int n2 = 2 * n;
    int e2 = 2 * e;
    int nblk = (e + EPB - 1) / EPB;              // 196 binning blocks
    int L = NBUK * nblk;                         // ~100K hist entries
    int ntile = (L + 1023) / 1024;               // 98 scan tiles (<=256)
    int nbuk_eff = (n2 + 255) >> 8;              // 391 non-empty buckets
    int ntiles16 = (n + 15) >> 4;                // 3125 proj tiles
    int projblks = (ntiles16 + 7) / 8;           // 391 proj blocks (8 tiles each)

    // proj chunk split across F2..F5
    int pc0 = projblks / 4, pc1 = projblks / 4, pc2 = projblks / 4;
    int pc3 = projblks - pc0 - pc1 - pc2;

    // workspace (32-bit words):
    // xw1[32n] xw2[32n] (bf16) s1 d1 s2 d2 [n each] wf[8192]
    // hist[L] hscan[L+1] part[1024] offs[n2+1] csr[e2] staging[e2]
    unsigned short* xw1 = (unsigned short*)d_ws;
    unsigned short* xw2 = xw1 + (size_t)n * DOUT;
    float* s1  = (float*)(xw2 + (size_t)n * DOUT);
    float* d1  = s1 + n;
    float* s2  = d1 + n;
    float* d2  = s2 + n;
    unsigned short* wf = (unsigned short*)(d2 + n);   // 16384 ushorts = 8192 words
    int* hist  = (int*)(wf + 16384);
    int* hscan = hist + (size_t)L;
    int* part  = hscan + (size_t)L + 1;
    int* offs  = part + 1024;
    int* csr   = offs + (size_t)n2 + 1;
    unsigned* staging = (unsigned*)(csr + (size_t)e2);

    fused1_kernel<<<8 + nblk, 256, 0, stream>>>(W1, W2, wf, src, dst, hist, e, n, nblk);

    fused2_kernel<<<ntile + pc0, 256, 0, stream>>>(hist, part, L, ntile,
        x, wf, as1, ad1, as2, ad2, xw1, xw2, s1, d1, s2, d2, n, 0);

    fused3_kernel<<<1 + pc1, 256, 0, stream>>>(part, ntile, hscan, L, e2,
        x, wf, as1, ad1, as2, ad2, xw1, xw2, s1, d1, s2, d2, n, pc0);

    fused4_kernel<<<ntile + pc2, 256, 0, stream>>>(hist, part, hscan, L, ntile,
        x, wf, as1, ad1, as2, ad2, xw1, xw2, s1, d1, s2, d2, n, pc0 + pc1);

    fused5_kernel<<<nblk + pc3, 256, 0, stream>>>(src, dst, hscan, staging, e, nblk,
        x, wf, as1, ad1, as2, ad2, xw1, xw2, s1, d1, s2, d2, n, pc0 + pc1 + pc2);

    buildcsr_kernel<<<nbuk_eff, 256, 0, stream>>>(hscan, staging, csr, offs, n2, e2, nblk);

    long long gthreads = (long long)n * 64;
    int gblocks = (int)((gthreads + 255) / 256);
    gather_kernel<<<gblocks, 256, 0, stream>>>(offs, csr, s1, d1, s2, d2,
                                               xw1, xw2, b1, b2, out, n);
}

// Round 16
// 101.045 us; speedup vs baseline: 1.1399x; 1.1399x over previous
//
#include <hip/hip_runtime.h>

#define DIN 128
#define DOUT 64
#define NEG_SLOPE 0.2f
#define ALPHA 0.5f
#define NBUK 512    // coarse buckets: bucket = seg >> 8, covers 2n = 100000 segments
#define EPB  4096   // edges per block in edgebin (196 blocks)
#define CAP  4608   // per-bucket staging capacity (mean 4096, +8 sigma)
#define BCCAP 6144  // buildcsr LDS staging cache (entries)

typedef __attribute__((ext_vector_type(8))) short bf16x8;
typedef __attribute__((ext_vector_type(4))) float f32x4;

__device__ __forceinline__ float lrelu(float x) { return x > 0.0f ? x : NEG_SLOPE * x; }

__device__ __forceinline__ unsigned short f2bf(float f) {
    unsigned u = __float_as_uint(f);
    unsigned r = (u + 0x7fffu + ((u >> 16) & 1u)) >> 16;
    return (unsigned short)r;
}
__device__ __forceinline__ float bf2f(unsigned short h) {
    return __uint_as_float((unsigned)h << 16);
}
__device__ __forceinline__ float readlane_f(float v, int l) {
    return __int_as_float(__builtin_amdgcn_readlane(__float_as_int(v), l));
}

// wfrag: bf16 B-fragments. wf[(mat*16 + kk*4 + t)*512 + l*8 + j], 32 KB total.
__device__ __forceinline__ void dev_wfrag(
    const float* __restrict__ W1, const float* __restrict__ W2,
    unsigned short* __restrict__ wf, int blk, int tid)
{
    int combo = blk * 4 + (tid >> 6);     // [0,32)
    int mat = combo >> 4;
    int kk = (combo >> 2) & 3;
    int t = combo & 3;
    int l = tid & 63;
    int g = l >> 4, c = l & 15;
    const float* W = mat ? W2 : W1;
    #pragma unroll
    for (int j = 0; j < 8; ++j) {
        float w = W[(kk * 32 + g * 8 + j) * DOUT + t * 16 + c];
        wf[(size_t)((mat * 16 + kk * 4 + t) * 512) + l * 8 + j] = f2bf(w);
    }
}

// proj via MFMA, plain bf16. 2 tiles (32 nodes) per wave; projblk in [0,391).
__device__ __forceinline__ void dev_proj(
    const float* __restrict__ x, const unsigned short* __restrict__ wf,
    const float* __restrict__ as1, const float* __restrict__ ad1,
    const float* __restrict__ as2, const float* __restrict__ ad2,
    unsigned short* __restrict__ xw1, unsigned short* __restrict__ xw2,
    float* __restrict__ s1, float* __restrict__ d1,
    float* __restrict__ s2, float* __restrict__ d2, int n, int projblk, int tid)
{
    int ntiles = (n + 15) >> 4;
    int tbase = projblk * 8 + (tid >> 6) * 2;
    if (tbase >= ntiles) return;
    int l = tid & 63;
    int g = l >> 4, c = l & 15;

    bf16x8 ah[2][4];
    #pragma unroll
    for (int u = 0; u < 2; ++u) {
        int arow = (tbase + u) * 16 + c;
        if (arow >= n) arow = n - 1;
        const float* xr = x + (size_t)arow * DIN + g * 8;
        #pragma unroll
        for (int kk = 0; kk < 4; ++kk) {
            float4 v0 = *(const float4*)(xr + kk * 32);
            float4 v1 = *(const float4*)(xr + kk * 32 + 4);
            float xv[8] = {v0.x, v0.y, v0.z, v0.w, v1.x, v1.y, v1.z, v1.w};
            #pragma unroll
            for (int j = 0; j < 8; ++j) ah[u][kk][j] = (short)f2bf(xv[j]);
        }
    }

    float vs1[2][4] = {}, vd1[2][4] = {}, vs2[2][4] = {}, vd2[2][4] = {};
    const bf16x8* wfv = (const bf16x8*)wf;

    #pragma unroll
    for (int t = 0; t < 4; ++t) {
        f32x4 C1[2] = {{0.f,0.f,0.f,0.f},{0.f,0.f,0.f,0.f}};
        f32x4 C2[2] = {{0.f,0.f,0.f,0.f},{0.f,0.f,0.f,0.f}};
        #pragma unroll
        for (int kk = 0; kk < 4; ++kk) {
            bf16x8 bh1 = wfv[(size_t)((0 * 16 + kk * 4 + t) * 64) + l];
            bf16x8 bh2 = wfv[(size_t)((1 * 16 + kk * 4 + t) * 64) + l];
            #pragma unroll
            for (int u = 0; u < 2; ++u) {
                C1[u] = __builtin_amdgcn_mfma_f32_16x16x32_bf16(ah[u][kk], bh1, C1[u], 0, 0, 0);
                C2[u] = __builtin_amdgcn_mfma_f32_16x16x32_bf16(ah[u][kk], bh2, C2[u], 0, 0, 0);
            }
        }
        float a1v = as1[t * 16 + c], a2v = ad1[t * 16 + c];
        float a3v = as2[t * 16 + c], a4v = ad2[t * 16 + c];
        #pragma unroll
        for (int u = 0; u < 2; ++u) {
            #pragma unroll
            for (int r = 0; r < 4; ++r) {
                vs1[u][r] = fmaf(C1[u][r], a1v, vs1[u][r]);
                vd1[u][r] = fmaf(C1[u][r], a2v, vd1[u][r]);
                vs2[u][r] = fmaf(C2[u][r], a3v, vs2[u][r]);
                vd2[u][r] = fmaf(C2[u][r], a4v, vd2[u][r]);
                int node = (tbase + u) * 16 + g * 4 + r;
                if (node < n) {
                    xw1[(size_t)node * DOUT + t * 16 + c] = f2bf(C1[u][r]);
                    xw2[(size_t)node * DOUT + t * 16 + c] = f2bf(C2[u][r]);
                }
            }
        }
    }
    #pragma unroll
    for (int off = 1; off < 16; off <<= 1) {
        #pragma unroll
        for (int u = 0; u < 2; ++u) {
            #pragma unroll
            for (int r = 0; r < 4; ++r) {
                vs1[u][r] += __shfl_xor(vs1[u][r], off);
                vd1[u][r] += __shfl_xor(vd1[u][r], off);
                vs2[u][r] += __shfl_xor(vs2[u][r], off);
                vd2[u][r] += __shfl_xor(vd2[u][r], off);
            }
        }
    }
    if (c == 0) {
        #pragma unroll
        for (int u = 0; u < 2; ++u) {
            #pragma unroll
            for (int r = 0; r < 4; ++r) {
                int node = (tbase + u) * 16 + g * 4 + r;
                if (node < n) {
                    s1[node] = vs1[u][r]; d1[node] = vd1[u][r];
                    s2[node] = vs2[u][r]; d2[node] = vd2[u][r];
                }
            }
        }
    }
}

// ---------------- fusedA: edgebin (count -> reserve -> scatter) ∪ wfrag.
// Per-bucket staging at fixed stride CAP; bases reserved via global atomics.
__global__ __launch_bounds__(256) void fusedA_kernel(
    const float* __restrict__ W1, const float* __restrict__ W2,
    unsigned short* __restrict__ wf,
    const int* __restrict__ src, const int* __restrict__ dst,
    int* __restrict__ bkcur, unsigned* __restrict__ staging,
    int e, int n, int nblk)
{
    __shared__ int cnt[NBUK];
    int blk = blockIdx.x, tid = threadIdx.x;
    if (blk >= nblk) { dev_wfrag(W1, W2, wf, blk - nblk, tid); return; }

    for (int b = tid; b < NBUK; b += 256) cnt[b] = 0;
    __syncthreads();
    int base = blk * EPB;
    // phase 1: count
    for (int k = 0; k < EPB / 256; ++k) {
        int t = base + k * 256 + tid;
        if (t < e) {
            atomicAdd(&cnt[dst[t] >> 8], 1);
            atomicAdd(&cnt[(n + src[t]) >> 8], 1);
        }
    }
    __syncthreads();
    // phase 2: reserve contiguous per-bucket ranges
    for (int b = tid; b < NBUK; b += 256) {
        int c = cnt[b];
        cnt[b] = c ? atomicAdd(&bkcur[b], c) : 0;
    }
    __syncthreads();
    // phase 3: scatter (edges re-read, L2-hot)
    for (int k = 0; k < EPB / 256; ++k) {
        int t = base + k * 256 + tid;
        if (t < e) {
            int s = src[t], d = dst[t];
            int bF = d >> 8;
            int pF = atomicAdd(&cnt[bF], 1);
            if (pF < CAP)
                staging[(size_t)bF * CAP + pF] = ((unsigned)(d & 255) << 16) | (unsigned)s;
            int segR = n + s;
            int bR = segR >> 8;
            int pR = atomicAdd(&cnt[bR], 1);
            if (pR < CAP)
                staging[(size_t)bR * CAP + pR] = ((unsigned)(segR & 255) << 16) | (unsigned)d;
        }
    }
}

// ---------------- fusedB: buildcsr (redundant in-block scan of bkcur) ∪ proj.
__global__ __launch_bounds__(256) void fusedB_kernel(
    const int* __restrict__ bkcur, const unsigned* __restrict__ staging,
    int* __restrict__ csr, int* __restrict__ offs,
    int n2, int e2, int nbuk_eff,
    const float* __restrict__ x, const unsigned short* __restrict__ wf,
    const float* __restrict__ as1, const float* __restrict__ ad1,
    const float* __restrict__ as2, const float* __restrict__ ad2,
    unsigned short* __restrict__ xw1, unsigned short* __restrict__ xw2,
    float* __restrict__ s1, float* __restrict__ d1,
    float* __restrict__ s2, float* __restrict__ d2, int n)
{
    __shared__ int cb[NBUK];     // cached bucket counts
    __shared__ int sc[256];      // pair-sum scan
    __shared__ int segcnt[256];
    __shared__ int segoff[256];
    __shared__ unsigned cache[BCCAP];
    int blk = blockIdx.x, tid = threadIdx.x;
    if (blk >= nbuk_eff) {
        dev_proj(x, wf, as1, ad1, as2, ad2, xw1, xw2, s1, d1, s2, d2, n,
                 blk - nbuk_eff, tid);
        return;
    }
    int b = blk;

    // global base lo = sum of bucket counts < b (in-block scan of bkcur[512])
    int v0 = bkcur[2 * tid], v1 = bkcur[2 * tid + 1];
    cb[2 * tid] = v0; cb[2 * tid + 1] = v1;
    int pairsum = v0 + v1;
    sc[tid] = pairsum;
    __syncthreads();
    for (int o = 1; o < 256; o <<= 1) {
        int u = (tid >= o) ? sc[tid - o] : 0;
        __syncthreads();
        sc[tid] += u;
        __syncthreads();
    }
    int q = b >> 1;
    int lo = (q > 0 ? sc[q - 1] : 0) + ((b & 1) ? cb[2 * q] : 0);
    int count = cb[b];
    int sbase = b * CAP;

    segcnt[tid] = 0;
    __syncthreads();
    if (count <= BCCAP) {
        for (int k = tid; k < count; k += 256) {
            unsigned st = staging[sbase + k];
            cache[k] = st;
            atomicAdd(&segcnt[st >> 16], 1);
        }
    } else {
        for (int k = tid; k < count; k += 256)
            atomicAdd(&segcnt[staging[sbase + k] >> 16], 1);
    }
    __syncthreads();
    if (tid < 64) {   // wave 0: exclusive scan of 256 seg counts (4 per lane)
        int a0 = segcnt[4 * tid], a1 = segcnt[4 * tid + 1];
        int a2 = segcnt[4 * tid + 2], a3 = segcnt[4 * tid + 3];
        int s = a0 + a1 + a2 + a3;
        int inc = s;
        #pragma unroll
        for (int off = 1; off < 64; off <<= 1) {
            int u = __shfl_up(inc, off);
            if (tid >= off) inc += u;
        }
        int excl = inc - s;
        segoff[4 * tid] = excl;
        segoff[4 * tid + 1] = excl + a0;
        segoff[4 * tid + 2] = excl + a0 + a1;
        segoff[4 * tid + 3] = excl + a0 + a1 + a2;
    }
    __syncthreads();
    {
        int seg = (b << 8) + tid;
        if (seg < n2) offs[seg] = lo + segoff[tid];
        segcnt[tid] = segoff[tid];   // running cursors
    }
    if (b == nbuk_eff - 1 && tid == 0) offs[n2] = e2;
    __syncthreads();
    if (count <= BCCAP) {
        for (int k = tid; k < count; k += 256) {
            unsigned st = cache[k];
            int pos = atomicAdd(&segcnt[st >> 16], 1);
            csr[lo + pos] = (int)(st & 0xFFFFu);
        }
    } else {
        for (int k = tid; k < count; k += 256) {
            unsigned st = staging[sbase + k];
            int pos = atomicAdd(&segcnt[st >> 16], 1);
            csr[lo + pos] = (int)(st & 0xFFFFu);
        }
    }
}

// ---------------- gather: ONE wave per node, both directions fused.
// No online max; denominators folded into the readlane accumulate loop.
__global__ __launch_bounds__(256) void gather_kernel(
    const int* __restrict__ offs, const int* __restrict__ csr,
    const float* __restrict__ s1, const float* __restrict__ d1,
    const float* __restrict__ s2, const float* __restrict__ d2,
    const unsigned short* __restrict__ xw1, const unsigned short* __restrict__ xw2,
    const float* __restrict__ b1, const float* __restrict__ b2,
    float* __restrict__ out, int n)
{
    int i = (blockIdx.x * 256 + threadIdx.x) >> 6;
    int lane = threadIdx.x & 63;
    if (i >= n) return;

    float d1i = d1[i], d2i = d2[i];
    int cF = offs[i],     endF = offs[i + 1];
    int cR = offs[n + i], endR = offs[n + i + 1];

    float pSF = __expf(lrelu(s1[i] + d1i));
    float pSR = __expf(lrelu(s2[i] + d2i));
    float lF0 = pSF, lF1 = 0.f, lR0 = pSR, lR1 = 0.f;
    float aF0 = pSF * bf2f(xw1[(size_t)i * DOUT + lane]), aF1 = 0.f, aF2 = 0.f, aF3 = 0.f;
    float aR0 = pSR * bf2f(xw2[(size_t)i * DOUT + lane]), aR1 = 0.f, aR2 = 0.f, aR3 = 0.f;

    while (cF < endF || cR < endR) {
        int cntF = endF - cF; cntF = cntF < 0 ? 0 : (cntF > 64 ? 64 : cntF);
        int cntR = endR - cR; cntR = cntR < 0 ? 0 : (cntR > 64 ? 64 : cntR);

        int jF = 0, jR = 0;
        float pF = 0.0f, pR = 0.0f;
        if (lane < cntF) { jF = csr[cF + lane]; pF = __expf(lrelu(s1[jF] + d1i)); }
        if (lane < cntR) { jR = csr[cR + lane]; pR = __expf(lrelu(s2[jR] + d2i)); }

        int tmax = cntF > cntR ? cntF : cntR;
        int t = 0;
        for (; t + 4 <= tmax; t += 4) {
            float pF0 = readlane_f(pF, t),     pF1 = readlane_f(pF, t + 1);
            float pF2 = readlane_f(pF, t + 2), pF3 = readlane_f(pF, t + 3);
            int   jF0 = __builtin_amdgcn_readlane(jF, t);
            int   jF1 = __builtin_amdgcn_readlane(jF, t + 1);
            int   jF2 = __builtin_amdgcn_readlane(jF, t + 2);
            int   jF3 = __builtin_amdgcn_readlane(jF, t + 3);
            float pR0 = readlane_f(pR, t),     pR1 = readlane_f(pR, t + 1);
            float pR2 = readlane_f(pR, t + 2), pR3 = readlane_f(pR, t + 3);
            int   jR0 = __builtin_amdgcn_readlane(jR, t);
            int   jR1 = __builtin_amdgcn_readlane(jR, t + 1);
            int   jR2 = __builtin_amdgcn_readlane(jR, t + 2);
            int   jR3 = __builtin_amdgcn_readlane(jR, t + 3);
            lF0 += pF0 + pF1; lF1 += pF2 + pF3;
            lR0 += pR0 + pR1; lR1 += pR2 + pR3;
            aF0 = fmaf(pF0, bf2f(xw1[(size_t)jF0 * DOUT + lane]), aF0);
            aF1 = fmaf(pF1, bf2f(xw1[(size_t)jF1 * DOUT + lane]), aF1);
            aF2 = fmaf(pF2, bf2f(xw1[(size_t)jF2 * DOUT + lane]), aF2);
            aF3 = fmaf(pF3, bf2f(xw1[(size_t)jF3 * DOUT + lane]), aF3);
            aR0 = fmaf(pR0, bf2f(xw2[(size_t)jR0 * DOUT + lane]), aR0);
            aR1 = fmaf(pR1, bf2f(xw2[(size_t)jR1 * DOUT + lane]), aR1);
            aR2 = fmaf(pR2, bf2f(xw2[(size_t)jR2 * DOUT + lane]), aR2);
            aR3 = fmaf(pR3, bf2f(xw2[(size_t)jR3 * DOUT + lane]), aR3);
        }
        for (; t < tmax; ++t) {
            float pF0 = readlane_f(pF, t);
            int   jF0 = __builtin_amdgcn_readlane(jF, t);
            float pR0 = readlane_f(pR, t);
            int   jR0 = __builtin_amdgcn_readlane(jR, t);
            lF0 += pF0; lR0 += pR0;
            aF0 = fmaf(pF0, bf2f(xw1[(size_t)jF0 * DOUT + lane]), aF0);
            aR0 = fmaf(pR0, bf2f(xw2[(size_t)jR0 * DOUT + lane]), aR0);
        }
        cF += cntF;
        cR += cntR;
    }

    float lF = lF0 + lF1, lR = lR0 + lR1;
    float resF = ((aF0 + aF1) + (aF2 + aF3)) / (lF + 1e-16f);
    float resR = ((aR0 + aR1) + (aR2 + aR3)) / (lR + 1e-16f);
    out[(size_t)i * DOUT + lane] =
        (1.0f - ALPHA) * (resF + b1[lane]) + ALPHA * (resR + b2[lane]);
}

extern "C" void kernel_launch(void* const* d_in, const int* in_sizes, int n_in,
                              void* d_out, int out_size, void* d_ws, size_t ws_size,
                              hipStream_t stream) {
    const float* x   = (const float*)d_in[0];
    const int*   ei  = (const int*)d_in[1];
    const float* W1  = (const float*)d_in[2];
    const float* as1 = (const float*)d_in[3];
    const float* ad1 = (const float*)d_in[4];
    const float* b1  = (const float*)d_in[5];
    const float* W2  = (const float*)d_in[6];
    const float* as2 = (const float*)d_in[7];
    const float* ad2 = (const float*)d_in[8];
    const float* b2  = (const float*)d_in[9];
    float* out = (float*)d_out;

    int n = in_sizes[0] / DIN;   // 50000  (< 65536 for 16-bit staging pack)
    int e = in_sizes[1] / 2;     // 800000
    const int* src = ei;
    const int* dst = ei + e;
    int n2 = 2 * n;
    int e2 = 2 * e;
    int nblk = (e + EPB - 1) / EPB;              // 196 edgebin blocks
    int nbuk_eff = (n2 + 255) >> 8;              // 391 non-empty buckets
    int ntiles16 = (n + 15) >> 4;                // 3125 proj tiles
    int projblks = (ntiles16 + 7) / 8;           // 391 proj blocks (8 tiles each)

    // workspace (32-bit words):
    // xw1[32n] xw2[32n] (bf16) s1 d1 s2 d2 [n each] wf[8192]
    // bkcur[NBUK] offs[n2+1] csr[e2] staging[NBUK*CAP]
    unsigned short* xw1 = (unsigned short*)d_ws;
    unsigned short* xw2 = xw1 + (size_t)n * DOUT;
    float* s1  = (float*)(xw2 + (size_t)n * DOUT);
    float* d1  = s1 + n;
    float* s2  = d1 + n;
    float* d2  = s2 + n;
    unsigned short* wf = (unsigned short*)(d2 + n);   // 16384 ushorts = 8192 words
    int* bkcur = (int*)(wf + 16384);
    int* offs  = bkcur + NBUK;
    int* csr   = offs + (size_t)n2 + 1;
    unsigned* staging = (unsigned*)(csr + (size_t)e2);

    hipMemsetAsync(bkcur, 0, NBUK * sizeof(int), stream);

    fusedA_kernel<<<nblk + 8, 256, 0, stream>>>(W1, W2, wf, src, dst,
                                                bkcur, staging, e, n, nblk);

    fusedB_kernel<<<nbuk_eff + projblks, 256, 0, stream>>>(
        bkcur, staging, csr, offs, n2, e2, nbuk_eff,
        x, wf, as1, ad1, as2, ad2, xw1, xw2, s1, d1, s2, d2, n);

    long long gthreads = (long long)n * 64;
    int gblocks = (int)((gthreads + 255) / 256);
    gather_kernel<<<gblocks, 256, 0, stream>>>(offs, csr, s1, d1, s2, d2,
                                               xw1, xw2, b1, b2, out, n);
}

// Round 17
// 97.687 us; speedup vs baseline: 1.1791x; 1.0344x over previous
//
#include <hip/hip_runtime.h>

#define DIN 128
#define DOUT 64
#define NEG_SLOPE 0.2f
#define ALPHA 0.5f
#define NBUK 512    // coarse buckets: bucket = seg >> 8, covers 2n = 100000 segments
#define EPB  4096   // edges per block in edgebin (196 blocks)
#define CAP  4608   // per-bucket staging capacity (mean 4096, +8 sigma)
#define BCCAP 6144  // buildcsr LDS staging cache (entries)

typedef __attribute__((ext_vector_type(8))) short bf16x8;
typedef __attribute__((ext_vector_type(4))) float f32x4;

__device__ __forceinline__ float lrelu(float x) { return x > 0.0f ? x : NEG_SLOPE * x; }

__device__ __forceinline__ unsigned short f2bf(float f) {
    unsigned u = __float_as_uint(f);
    unsigned r = (u + 0x7fffu + ((u >> 16) & 1u)) >> 16;
    return (unsigned short)r;
}
__device__ __forceinline__ float bf2f(unsigned short h) {
    return __uint_as_float((unsigned)h << 16);
}
// pack two f32 -> two bf16 (RNE), src0 in low 16, src1 in high 16 [T12]
__device__ __forceinline__ unsigned cvt_pk_bf16(float a, float b) {
    unsigned r;
    asm("v_cvt_pk_bf16_f32 %0, %1, %2" : "=v"(r) : "v"(a), "v"(b));
    return r;
}
__device__ __forceinline__ float readlane_f(float v, int l) {
    return __int_as_float(__builtin_amdgcn_readlane(__float_as_int(v), l));
}

// wfrag: bf16 B-fragments. wf[(mat*16 + kk*4 + t)*512 + l*8 + j], 32 KB total.
__device__ __forceinline__ void dev_wfrag(
    const float* __restrict__ W1, const float* __restrict__ W2,
    unsigned short* __restrict__ wf, int blk, int tid)
{
    int combo = blk * 4 + (tid >> 6);     // [0,32)
    int mat = combo >> 4;
    int kk = (combo >> 2) & 3;
    int t = combo & 3;
    int l = tid & 63;
    int g = l >> 4, c = l & 15;
    const float* W = mat ? W2 : W1;
    #pragma unroll
    for (int j = 0; j < 8; ++j) {
        float w = W[(kk * 32 + g * 8 + j) * DOUT + t * 16 + c];
        wf[(size_t)((mat * 16 + kk * 4 + t) * 512) + l * 8 + j] = f2bf(w);
    }
}

// proj via MFMA, plain bf16. 2 tiles (32 nodes) per wave; projblk in [0,391).
__device__ __forceinline__ void dev_proj(
    const float* __restrict__ x, const unsigned short* __restrict__ wf,
    const float* __restrict__ as1, const float* __restrict__ ad1,
    const float* __restrict__ as2, const float* __restrict__ ad2,
    unsigned short* __restrict__ xw1, unsigned short* __restrict__ xw2,
    float* __restrict__ s1, float* __restrict__ d1,
    float* __restrict__ s2, float* __restrict__ d2, int n, int projblk, int tid)
{
    int ntiles = (n + 15) >> 4;
    int tbase = projblk * 8 + (tid >> 6) * 2;
    if (tbase >= ntiles) return;
    int l = tid & 63;
    int g = l >> 4, c = l & 15;

    bf16x8 ah[2][4];
    #pragma unroll
    for (int u = 0; u < 2; ++u) {
        int arow = (tbase + u) * 16 + c;
        if (arow >= n) arow = n - 1;
        const float* xr = x + (size_t)arow * DIN + g * 8;
        #pragma unroll
        for (int kk = 0; kk < 4; ++kk) {
            float4 v0 = *(const float4*)(xr + kk * 32);
            float4 v1 = *(const float4*)(xr + kk * 32 + 4);
            unsigned* dw = (unsigned*)&ah[u][kk];
            dw[0] = cvt_pk_bf16(v0.x, v0.y);
            dw[1] = cvt_pk_bf16(v0.z, v0.w);
            dw[2] = cvt_pk_bf16(v1.x, v1.y);
            dw[3] = cvt_pk_bf16(v1.z, v1.w);
        }
    }

    float vs1[2][4] = {}, vd1[2][4] = {}, vs2[2][4] = {}, vd2[2][4] = {};
    const bf16x8* wfv = (const bf16x8*)wf;

    #pragma unroll
    for (int t = 0; t < 4; ++t) {
        f32x4 C1[2] = {{0.f,0.f,0.f,0.f},{0.f,0.f,0.f,0.f}};
        f32x4 C2[2] = {{0.f,0.f,0.f,0.f},{0.f,0.f,0.f,0.f}};
        #pragma unroll
        for (int kk = 0; kk < 4; ++kk) {
            bf16x8 bh1 = wfv[(size_t)((0 * 16 + kk * 4 + t) * 64) + l];
            bf16x8 bh2 = wfv[(size_t)((1 * 16 + kk * 4 + t) * 64) + l];
            #pragma unroll
            for (int u = 0; u < 2; ++u) {
                C1[u] = __builtin_amdgcn_mfma_f32_16x16x32_bf16(ah[u][kk], bh1, C1[u], 0, 0, 0);
                C2[u] = __builtin_amdgcn_mfma_f32_16x16x32_bf16(ah[u][kk], bh2, C2[u], 0, 0, 0);
            }
        }
        float a1v = as1[t * 16 + c], a2v = ad1[t * 16 + c];
        float a3v = as2[t * 16 + c], a4v = ad2[t * 16 + c];
        #pragma unroll
        for (int u = 0; u < 2; ++u) {
            #pragma unroll
            for (int r = 0; r < 4; ++r) {
                vs1[u][r] = fmaf(C1[u][r], a1v, vs1[u][r]);
                vd1[u][r] = fmaf(C1[u][r], a2v, vd1[u][r]);
                vs2[u][r] = fmaf(C2[u][r], a3v, vs2[u][r]);
                vd2[u][r] = fmaf(C2[u][r], a4v, vd2[u][r]);
            }
            unsigned w1a = cvt_pk_bf16(C1[u][0], C1[u][1]);
            unsigned w1b = cvt_pk_bf16(C1[u][2], C1[u][3]);
            unsigned w2a = cvt_pk_bf16(C2[u][0], C2[u][1]);
            unsigned w2b = cvt_pk_bf16(C2[u][2], C2[u][3]);
            unsigned short v1s[4] = {(unsigned short)w1a, (unsigned short)(w1a >> 16),
                                     (unsigned short)w1b, (unsigned short)(w1b >> 16)};
            unsigned short v2s[4] = {(unsigned short)w2a, (unsigned short)(w2a >> 16),
                                     (unsigned short)w2b, (unsigned short)(w2b >> 16)};
            #pragma unroll
            for (int r = 0; r < 4; ++r) {
                int node = (tbase + u) * 16 + g * 4 + r;
                if (node < n) {
                    xw1[(size_t)node * DOUT + t * 16 + c] = v1s[r];
                    xw2[(size_t)node * DOUT + t * 16 + c] = v2s[r];
                }
            }
        }
    }
    #pragma unroll
    for (int off = 1; off < 16; off <<= 1) {
        #pragma unroll
        for (int u = 0; u < 2; ++u) {
            #pragma unroll
            for (int r = 0; r < 4; ++r) {
                vs1[u][r] += __shfl_xor(vs1[u][r], off);
                vd1[u][r] += __shfl_xor(vd1[u][r], off);
                vs2[u][r] += __shfl_xor(vs2[u][r], off);
                vd2[u][r] += __shfl_xor(vd2[u][r], off);
            }
        }
    }
    if (c == 0) {
        #pragma unroll
        for (int u = 0; u < 2; ++u) {
            #pragma unroll
            for (int r = 0; r < 4; ++r) {
                int node = (tbase + u) * 16 + g * 4 + r;
                if (node < n) {
                    s1[node] = vs1[u][r]; d1[node] = vd1[u][r];
                    s2[node] = vs2[u][r]; d2[node] = vd2[u][r];
                }
            }
        }
    }
}

// ---------------- fusedA: edgebin (count -> reserve -> scatter) ∪ wfrag.
// Edges cached in LDS during count; scatter reads LDS (no global re-read).
__global__ __launch_bounds__(256) void fusedA_kernel(
    const float* __restrict__ W1, const float* __restrict__ W2,
    unsigned short* __restrict__ wf,
    const int* __restrict__ src, const int* __restrict__ dst,
    int* __restrict__ bkcur, unsigned* __restrict__ staging,
    int e, int n, int nblk)
{
    __shared__ int cnt[NBUK];   // 2 KB
    __shared__ int es[EPB];     // 16 KB
    __shared__ int ed[EPB];     // 16 KB
    int blk = blockIdx.x, tid = threadIdx.x;
    if (blk >= nblk) { dev_wfrag(W1, W2, wf, blk - nblk, tid); return; }

    for (int b = tid; b < NBUK; b += 256) cnt[b] = 0;
    __syncthreads();
    int base = blk * EPB;
    // phase 1: count + cache edges in LDS
    for (int k = 0; k < EPB / 256; ++k) {
        int li = k * 256 + tid;
        int t = base + li;
        int s = -1, d = -1;
        if (t < e) {
            s = src[t]; d = dst[t];
            atomicAdd(&cnt[d >> 8], 1);
            atomicAdd(&cnt[(n + s) >> 8], 1);
        }
        es[li] = s; ed[li] = d;
    }
    __syncthreads();
    // phase 2: reserve contiguous per-bucket ranges
    for (int b = tid; b < NBUK; b += 256) {
        int c = cnt[b];
        cnt[b] = c ? atomicAdd(&bkcur[b], c) : 0;
    }
    __syncthreads();
    // phase 3: scatter from LDS
    for (int k = 0; k < EPB / 256; ++k) {
        int li = k * 256 + tid;
        int s = es[li], d = ed[li];
        if (s >= 0) {
            int bF = d >> 8;
            int pF = atomicAdd(&cnt[bF], 1);
            if (pF < CAP)
                staging[(size_t)bF * CAP + pF] = ((unsigned)(d & 255) << 16) | (unsigned)s;
            int segR = n + s;
            int bR = segR >> 8;
            int pR = atomicAdd(&cnt[bR], 1);
            if (pR < CAP)
                staging[(size_t)bR * CAP + pR] = ((unsigned)(segR & 255) << 16) | (unsigned)d;
        }
    }
}

// ---------------- fusedB: buildcsr (redundant in-block scan of bkcur) ∪ proj.
__global__ __launch_bounds__(256) void fusedB_kernel(
    const int* __restrict__ bkcur, const unsigned* __restrict__ staging,
    int* __restrict__ csr, int* __restrict__ offs,
    int n2, int e2, int nbuk_eff,
    const float* __restrict__ x, const unsigned short* __restrict__ wf,
    const float* __restrict__ as1, const float* __restrict__ ad1,
    const float* __restrict__ as2, const float* __restrict__ ad2,
    unsigned short* __restrict__ xw1, unsigned short* __restrict__ xw2,
    float* __restrict__ s1, float* __restrict__ d1,
    float* __restrict__ s2, float* __restrict__ d2, int n)
{
    __shared__ int cb[NBUK];     // cached bucket counts
    __shared__ int sc[256];      // pair-sum scan
    __shared__ int segcnt[256];
    __shared__ int segoff[256];
    __shared__ unsigned cache[BCCAP];
    int blk = blockIdx.x, tid = threadIdx.x;
    if (blk >= nbuk_eff) {
        dev_proj(x, wf, as1, ad1, as2, ad2, xw1, xw2, s1, d1, s2, d2, n,
                 blk - nbuk_eff, tid);
        return;
    }
    int b = blk;

    // global base lo = sum of bucket counts < b (in-block scan of bkcur[512])
    int v0 = bkcur[2 * tid], v1 = bkcur[2 * tid + 1];
    cb[2 * tid] = v0; cb[2 * tid + 1] = v1;
    int pairsum = v0 + v1;
    sc[tid] = pairsum;
    __syncthreads();
    for (int o = 1; o < 256; o <<= 1) {
        int u = (tid >= o) ? sc[tid - o] : 0;
        __syncthreads();
        sc[tid] += u;
        __syncthreads();
    }
    int q = b >> 1;
    int lo = (q > 0 ? sc[q - 1] : 0) + ((b & 1) ? cb[2 * q] : 0);
    int count = cb[b];
    int sbase = b * CAP;

    segcnt[tid] = 0;
    __syncthreads();
    if (count <= BCCAP) {
        for (int k = tid; k < count; k += 256) {
            unsigned st = staging[sbase + k];
            cache[k] = st;
            atomicAdd(&segcnt[st >> 16], 1);
        }
    } else {
        for (int k = tid; k < count; k += 256)
            atomicAdd(&segcnt[staging[sbase + k] >> 16], 1);
    }
    __syncthreads();
    if (tid < 64) {   // wave 0: exclusive scan of 256 seg counts (4 per lane)
        int a0 = segcnt[4 * tid], a1 = segcnt[4 * tid + 1];
        int a2 = segcnt[4 * tid + 2], a3 = segcnt[4 * tid + 3];
        int s = a0 + a1 + a2 + a3;
        int inc = s;
        #pragma unroll
        for (int off = 1; off < 64; off <<= 1) {
            int u = __shfl_up(inc, off);
            if (tid >= off) inc += u;
        }
        int excl = inc - s;
        segoff[4 * tid] = excl;
        segoff[4 * tid + 1] = excl + a0;
        segoff[4 * tid + 2] = excl + a0 + a1;
        segoff[4 * tid + 3] = excl + a0 + a1 + a2;
    }
    __syncthreads();
    {
        int seg = (b << 8) + tid;
        if (seg < n2) offs[seg] = lo + segoff[tid];
        segcnt[tid] = segoff[tid];   // running cursors
    }
    if (b == nbuk_eff - 1 && tid == 0) offs[n2] = e2;
    __syncthreads();
    if (count <= BCCAP) {
        for (int k = tid; k < count; k += 256) {
            unsigned st = cache[k];
            int pos = atomicAdd(&segcnt[st >> 16], 1);
            csr[lo + pos] = (int)(st & 0xFFFFu);
        }
    } else {
        for (int k = tid; k < count; k += 256) {
            unsigned st = staging[sbase + k];
            int pos = atomicAdd(&segcnt[st >> 16], 1);
            csr[lo + pos] = (int)(st & 0xFFFFu);
        }
    }
}

// ---------------- gather: ONE wave per node, both directions fused.
// 8 accumulate chains per direction; loop rounded to 8 (idle slots p==0, j==0
// -> row-0 load is cache-hot, fma adds exactly 0; bit-identical, no tail loop).
__global__ __launch_bounds__(256) void gather_kernel(
    const int* __restrict__ offs, const int* __restrict__ csr,
    const float* __restrict__ s1, const float* __restrict__ d1,
    const float* __restrict__ s2, const float* __restrict__ d2,
    const unsigned short* __restrict__ xw1, const unsigned short* __restrict__ xw2,
    const float* __restrict__ b1, const float* __restrict__ b2,
    float* __restrict__ out, int n)
{
    int i = (blockIdx.x * 256 + threadIdx.x) >> 6;
    int lane = threadIdx.x & 63;
    if (i >= n) return;

    float d1i = d1[i], d2i = d2[i];
    int cF = offs[i],     endF = offs[i + 1];
    int cR = offs[n + i], endR = offs[n + i + 1];

    float pSF = __expf(lrelu(s1[i] + d1i));
    float pSR = __expf(lrelu(s2[i] + d2i));
    float lFa = pSF, lFb = 0.f, lRa = pSR, lRb = 0.f;
    float aF[8] = {}, aR[8] = {};
    aF[0] = pSF * bf2f(xw1[(size_t)i * DOUT + lane]);
    aR[0] = pSR * bf2f(xw2[(size_t)i * DOUT + lane]);

    while (cF < endF || cR < endR) {
        int cntF = endF - cF; cntF = cntF < 0 ? 0 : (cntF > 64 ? 64 : cntF);
        int cntR = endR - cR; cntR = cntR < 0 ? 0 : (cntR > 64 ? 64 : cntR);

        int jF = 0, jR = 0;
        float pF = 0.0f, pR = 0.0f;
        if (lane < cntF) { jF = csr[cF + lane]; pF = __expf(lrelu(s1[jF] + d1i)); }
        if (lane < cntR) { jR = csr[cR + lane]; pR = __expf(lrelu(s2[jR] + d2i)); }

        int tmax = cntF > cntR ? cntF : cntR;
        int tmax8 = (tmax + 7) & ~7;
        for (int t = 0; t < tmax8; t += 8) {
            float pFs[8], pRs[8]; int jFs[8], jRs[8];
            #pragma unroll
            for (int u = 0; u < 8; ++u) {
                pFs[u] = readlane_f(pF, t + u);
                jFs[u] = __builtin_amdgcn_readlane(jF, t + u);
                pRs[u] = readlane_f(pR, t + u);
                jRs[u] = __builtin_amdgcn_readlane(jR, t + u);
            }
            float vF[8], vR[8];
            #pragma unroll
            for (int u = 0; u < 8; ++u) {
                vF[u] = bf2f(xw1[(size_t)jFs[u] * DOUT + lane]);
                vR[u] = bf2f(xw2[(size_t)jRs[u] * DOUT + lane]);
            }
            #pragma unroll
            for (int u = 0; u < 8; ++u) {
                aF[u] = fmaf(pFs[u], vF[u], aF[u]);
                aR[u] = fmaf(pRs[u], vR[u], aR[u]);
            }
            lFa += (pFs[0] + pFs[1]) + (pFs[2] + pFs[3]);
            lFb += (pFs[4] + pFs[5]) + (pFs[6] + pFs[7]);
            lRa += (pRs[0] + pRs[1]) + (pRs[2] + pRs[3]);
            lRb += (pRs[4] + pRs[5]) + (pRs[6] + pRs[7]);
        }
        cF += cntF;
        cR += cntR;
    }

    float lF = lFa + lFb, lR = lRa + lRb;
    float sF = ((aF[0] + aF[1]) + (aF[2] + aF[3])) + ((aF[4] + aF[5]) + (aF[6] + aF[7]));
    float sR = ((aR[0] + aR[1]) + (aR[2] + aR[3])) + ((aR[4] + aR[5]) + (aR[6] + aR[7]));
    float resF = sF / (lF + 1e-16f);
    float resR = sR / (lR + 1e-16f);
    out[(size_t)i * DOUT + lane] =
        (1.0f - ALPHA) * (resF + b1[lane]) + ALPHA * (resR + b2[lane]);
}

extern "C" void kernel_launch(void* const* d_in, const int* in_sizes, int n_in,
                              void* d_out, int out_size, void* d_ws, size_t ws_size,
                              hipStream_t stream) {
    const float* x   = (const float*)d_in[0];
    const int*   ei  = (const int*)d_in[1];
    const float* W1  = (const float*)d_in[2];
    const float* as1 = (const float*)d_in[3];
    const float* ad1 = (const float*)d_in[4];
    const float* b1  = (const float*)d_in[5];
    const float* W2  = (const float*)d_in[6];
    const float* as2 = (const float*)d_in[7];
    const float* ad2 = (const float*)d_in[8];
    const float* b2  = (const float*)d_in[9];
    float* out = (float*)d_out;

    int n = in_sizes[0] / DIN;   // 50000  (< 65536 for 16-bit staging pack)
    int e = in_sizes[1] / 2;     // 800000
    const int* src = ei;
    const int* dst = ei + e;
    int n2 = 2 * n;
    int e2 = 2 * e;
    int nblk = (e + EPB - 1) / EPB;              // 196 edgebin blocks
    int nbuk_eff = (n2 + 255) >> 8;              // 391 non-empty buckets
    int ntiles16 = (n + 15) >> 4;                // 3125 proj tiles
    int projblks = (ntiles16 + 7) / 8;           // 391 proj blocks (8 tiles each)

    // workspace (32-bit words):
    // xw1[32n] xw2[32n] (bf16) s1 d1 s2 d2 [n each] wf[8192]
    // bkcur[NBUK] offs[n2+1] csr[e2] staging[NBUK*CAP]
    unsigned short* xw1 = (unsigned short*)d_ws;
    unsigned short* xw2 = xw1 + (size_t)n * DOUT;
    float* s1  = (float*)(xw2 + (size_t)n * DOUT);
    float* d1  = s1 + n;
    float* s2  = d1 + n;
    float* d2  = s2 + n;
    unsigned short* wf = (unsigned short*)(d2 + n);   // 16384 ushorts = 8192 words
    int* bkcur = (int*)(wf + 16384);
    int* offs  = bkcur + NBUK;
    int* csr   = offs + (size_t)n2 + 1;
    unsigned* staging = (unsigned*)(csr + (size_t)e2);

    hipMemsetAsync(bkcur, 0, NBUK * sizeof(int), stream);

    fusedA_kernel<<<nblk + 8, 256, 0, stream>>>(W1, W2, wf, src, dst,
                                                bkcur, staging, e, n, nblk);

    fusedB_kernel<<<nbuk_eff + projblks, 256, 0, stream>>>(
        bkcur, staging, csr, offs, n2, e2, nbuk_eff,
        x, wf, as1, ad1, as2, ad2, xw1, xw2, s1, d1, s2, d2, n);

    long long gthreads = (long long)n * 64;
    int gblocks = (int)((gthreads + 255) / 256);
    gather_kernel<<<gblocks, 256, 0, stream>>>(offs, csr, s1, d1, s2, d2,
                                               xw1, xw2, b1, b2, out, n);
}

// Round 18
// 96.228 us; speedup vs baseline: 1.1970x; 1.0152x over previous
//
#include <hip/hip_runtime.h>

#define DIN 128
#define DOUT 64
#define NEG_SLOPE 0.2f
#define ALPHA 0.5f
#define NBUK 512    // coarse buckets: bucket = seg >> 8, covers 2n = 100000 segments
#define EPB  4096   // edges per block in edgebin (196 blocks)
#define CAP  4608   // per-bucket staging capacity (mean 4096, +8 sigma)
#define BCCAP 6144  // buildcsr LDS staging cache (entries)

typedef __attribute__((ext_vector_type(8))) short bf16x8;
typedef __attribute__((ext_vector_type(4))) float f32x4;

__device__ __forceinline__ float lrelu(float x) { return x > 0.0f ? x : NEG_SLOPE * x; }

__device__ __forceinline__ unsigned short f2bf(float f) {
    unsigned u = __float_as_uint(f);
    unsigned r = (u + 0x7fffu + ((u >> 16) & 1u)) >> 16;
    return (unsigned short)r;
}
__device__ __forceinline__ float bf2f(unsigned short h) {
    return __uint_as_float((unsigned)h << 16);
}
// pack two f32 -> two bf16 (RNE), src0 in low 16, src1 in high 16 [T12]
__device__ __forceinline__ unsigned cvt_pk_bf16(float a, float b) {
    unsigned r;
    asm("v_cvt_pk_bf16_f32 %0, %1, %2" : "=v"(r) : "v"(a), "v"(b));
    return r;
}
__device__ __forceinline__ float readlane_f(float v, int l) {
    return __int_as_float(__builtin_amdgcn_readlane(__float_as_int(v), l));
}

// wfrag: bf16 B-fragments. wf[(mat*16 + kk*4 + t)*512 + l*8 + j], 32 KB total.
__device__ __forceinline__ void dev_wfrag(
    const float* __restrict__ W1, const float* __restrict__ W2,
    unsigned short* __restrict__ wf, int blk, int tid)
{
    int combo = blk * 4 + (tid >> 6);     // [0,32)
    int mat = combo >> 4;
    int kk = (combo >> 2) & 3;
    int t = combo & 3;
    int l = tid & 63;
    int g = l >> 4, c = l & 15;
    const float* W = mat ? W2 : W1;
    #pragma unroll
    for (int j = 0; j < 8; ++j) {
        float w = W[(kk * 32 + g * 8 + j) * DOUT + t * 16 + c];
        wf[(size_t)((mat * 16 + kk * 4 + t) * 512) + l * 8 + j] = f2bf(w);
    }
}

// proj via MFMA, plain bf16. 2 tiles (32 nodes) per wave; projblk in [0,391).
__device__ __forceinline__ void dev_proj(
    const float* __restrict__ x, const unsigned short* __restrict__ wf,
    const float* __restrict__ as1, const float* __restrict__ ad1,
    const float* __restrict__ as2, const float* __restrict__ ad2,
    unsigned short* __restrict__ xw1, unsigned short* __restrict__ xw2,
    float* __restrict__ s1, float* __restrict__ d1,
    float* __restrict__ s2, float* __restrict__ d2, int n, int projblk, int tid)
{
    int ntiles = (n + 15) >> 4;
    int tbase = projblk * 8 + (tid >> 6) * 2;
    if (tbase >= ntiles) return;
    int l = tid & 63;
    int g = l >> 4, c = l & 15;

    bf16x8 ah[2][4];
    #pragma unroll
    for (int u = 0; u < 2; ++u) {
        int arow = (tbase + u) * 16 + c;
        if (arow >= n) arow = n - 1;
        const float* xr = x + (size_t)arow * DIN + g * 8;
        #pragma unroll
        for (int kk = 0; kk < 4; ++kk) {
            float4 v0 = *(const float4*)(xr + kk * 32);
            float4 v1 = *(const float4*)(xr + kk * 32 + 4);
            unsigned* dw = (unsigned*)&ah[u][kk];
            dw[0] = cvt_pk_bf16(v0.x, v0.y);
            dw[1] = cvt_pk_bf16(v0.z, v0.w);
            dw[2] = cvt_pk_bf16(v1.x, v1.y);
            dw[3] = cvt_pk_bf16(v1.z, v1.w);
        }
    }

    float vs1[2][4] = {}, vd1[2][4] = {}, vs2[2][4] = {}, vd2[2][4] = {};
    const bf16x8* wfv = (const bf16x8*)wf;

    #pragma unroll
    for (int t = 0; t < 4; ++t) {
        f32x4 C1[2] = {{0.f,0.f,0.f,0.f},{0.f,0.f,0.f,0.f}};
        f32x4 C2[2] = {{0.f,0.f,0.f,0.f},{0.f,0.f,0.f,0.f}};
        #pragma unroll
        for (int kk = 0; kk < 4; ++kk) {
            bf16x8 bh1 = wfv[(size_t)((0 * 16 + kk * 4 + t) * 64) + l];
            bf16x8 bh2 = wfv[(size_t)((1 * 16 + kk * 4 + t) * 64) + l];
            #pragma unroll
            for (int u = 0; u < 2; ++u) {
                C1[u] = __builtin_amdgcn_mfma_f32_16x16x32_bf16(ah[u][kk], bh1, C1[u], 0, 0, 0);
                C2[u] = __builtin_amdgcn_mfma_f32_16x16x32_bf16(ah[u][kk], bh2, C2[u], 0, 0, 0);
            }
        }
        float a1v = as1[t * 16 + c], a2v = ad1[t * 16 + c];
        float a3v = as2[t * 16 + c], a4v = ad2[t * 16 + c];
        #pragma unroll
        for (int u = 0; u < 2; ++u) {
            #pragma unroll
            for (int r = 0; r < 4; ++r) {
                vs1[u][r] = fmaf(C1[u][r], a1v, vs1[u][r]);
                vd1[u][r] = fmaf(C1[u][r], a2v, vd1[u][r]);
                vs2[u][r] = fmaf(C2[u][r], a3v, vs2[u][r]);
                vd2[u][r] = fmaf(C2[u][r], a4v, vd2[u][r]);
            }
            unsigned w1a = cvt_pk_bf16(C1[u][0], C1[u][1]);
            unsigned w1b = cvt_pk_bf16(C1[u][2], C1[u][3]);
            unsigned w2a = cvt_pk_bf16(C2[u][0], C2[u][1]);
            unsigned w2b = cvt_pk_bf16(C2[u][2], C2[u][3]);
            unsigned short v1s[4] = {(unsigned short)w1a, (unsigned short)(w1a >> 16),
                                     (unsigned short)w1b, (unsigned short)(w1b >> 16)};
            unsigned short v2s[4] = {(unsigned short)w2a, (unsigned short)(w2a >> 16),
                                     (unsigned short)w2b, (unsigned short)(w2b >> 16)};
            #pragma unroll
            for (int r = 0; r < 4; ++r) {
                int node = (tbase + u) * 16 + g * 4 + r;
                if (node < n) {
                    xw1[(size_t)node * DOUT + t * 16 + c] = v1s[r];
                    xw2[(size_t)node * DOUT + t * 16 + c] = v2s[r];
                }
            }
        }
    }
    #pragma unroll
    for (int off = 1; off < 16; off <<= 1) {
        #pragma unroll
        for (int u = 0; u < 2; ++u) {
            #pragma unroll
            for (int r = 0; r < 4; ++r) {
                vs1[u][r] += __shfl_xor(vs1[u][r], off);
                vd1[u][r] += __shfl_xor(vd1[u][r], off);
                vs2[u][r] += __shfl_xor(vs2[u][r], off);
                vd2[u][r] += __shfl_xor(vd2[u][r], off);
            }
        }
    }
    if (c == 0) {
        #pragma unroll
        for (int u = 0; u < 2; ++u) {
            #pragma unroll
            for (int r = 0; r < 4; ++r) {
                int node = (tbase + u) * 16 + g * 4 + r;
                if (node < n) {
                    s1[node] = vs1[u][r]; d1[node] = vd1[u][r];
                    s2[node] = vs2[u][r]; d2[node] = vd2[u][r];
                }
            }
        }
    }
}

// ---------------- fusedA: edgebin (count -> reserve -> scatter) ∪ wfrag.
// Edges cached in LDS during count; scatter reads LDS (no global re-read).
__global__ __launch_bounds__(256) void fusedA_kernel(
    const float* __restrict__ W1, const float* __restrict__ W2,
    unsigned short* __restrict__ wf,
    const int* __restrict__ src, const int* __restrict__ dst,
    int* __restrict__ bkcur, unsigned* __restrict__ staging,
    int e, int n, int nblk)
{
    __shared__ int cnt[NBUK];   // 2 KB
    __shared__ int es[EPB];     // 16 KB
    __shared__ int ed[EPB];     // 16 KB
    int blk = blockIdx.x, tid = threadIdx.x;
    if (blk >= nblk) { dev_wfrag(W1, W2, wf, blk - nblk, tid); return; }

    for (int b = tid; b < NBUK; b += 256) cnt[b] = 0;
    __syncthreads();
    int base = blk * EPB;
    // phase 1: count + cache edges in LDS
    for (int k = 0; k < EPB / 256; ++k) {
        int li = k * 256 + tid;
        int t = base + li;
        int s = -1, d = -1;
        if (t < e) {
            s = src[t]; d = dst[t];
            atomicAdd(&cnt[d >> 8], 1);
            atomicAdd(&cnt[(n + s) >> 8], 1);
        }
        es[li] = s; ed[li] = d;
    }
    __syncthreads();
    // phase 2: reserve contiguous per-bucket ranges
    for (int b = tid; b < NBUK; b += 256) {
        int c = cnt[b];
        cnt[b] = c ? atomicAdd(&bkcur[b], c) : 0;
    }
    __syncthreads();
    // phase 3: scatter from LDS
    for (int k = 0; k < EPB / 256; ++k) {
        int li = k * 256 + tid;
        int s = es[li], d = ed[li];
        if (s >= 0) {
            int bF = d >> 8;
            int pF = atomicAdd(&cnt[bF], 1);
            if (pF < CAP)
                staging[(size_t)bF * CAP + pF] = ((unsigned)(d & 255) << 16) | (unsigned)s;
            int segR = n + s;
            int bR = segR >> 8;
            int pR = atomicAdd(&cnt[bR], 1);
            if (pR < CAP)
                staging[(size_t)bR * CAP + pR] = ((unsigned)(segR & 255) << 16) | (unsigned)d;
        }
    }
}

// ---------------- fusedB: buildcsr (redundant in-block scan of bkcur) ∪ proj.
__global__ __launch_bounds__(256) void fusedB_kernel(
    const int* __restrict__ bkcur, const unsigned* __restrict__ staging,
    int* __restrict__ csr, int* __restrict__ offs,
    int n2, int e2, int nbuk_eff,
    const float* __restrict__ x, const unsigned short* __restrict__ wf,
    const float* __restrict__ as1, const float* __restrict__ ad1,
    const float* __restrict__ as2, const float* __restrict__ ad2,
    unsigned short* __restrict__ xw1, unsigned short* __restrict__ xw2,
    float* __restrict__ s1, float* __restrict__ d1,
    float* __restrict__ s2, float* __restrict__ d2, int n)
{
    __shared__ int cb[NBUK];     // cached bucket counts
    __shared__ int sc[256];      // pair-sum scan
    __shared__ int segcnt[256];
    __shared__ int segoff[256];
    __shared__ unsigned cache[BCCAP];
    int blk = blockIdx.x, tid = threadIdx.x;
    if (blk >= nbuk_eff) {
        dev_proj(x, wf, as1, ad1, as2, ad2, xw1, xw2, s1, d1, s2, d2, n,
                 blk - nbuk_eff, tid);
        return;
    }
    int b = blk;

    // global base lo = sum of bucket counts < b (in-block scan of bkcur[512])
    int v0 = bkcur[2 * tid], v1 = bkcur[2 * tid + 1];
    cb[2 * tid] = v0; cb[2 * tid + 1] = v1;
    int pairsum = v0 + v1;
    sc[tid] = pairsum;
    __syncthreads();
    for (int o = 1; o < 256; o <<= 1) {
        int u = (tid >= o) ? sc[tid - o] : 0;
        __syncthreads();
        sc[tid] += u;
        __syncthreads();
    }
    int q = b >> 1;
    int lo = (q > 0 ? sc[q - 1] : 0) + ((b & 1) ? cb[2 * q] : 0);
    int count = cb[b];
    int sbase = b * CAP;

    segcnt[tid] = 0;
    __syncthreads();
    if (count <= BCCAP) {
        for (int k = tid; k < count; k += 256) {
            unsigned st = staging[sbase + k];
            cache[k] = st;
            atomicAdd(&segcnt[st >> 16], 1);
        }
    } else {
        for (int k = tid; k < count; k += 256)
            atomicAdd(&segcnt[staging[sbase + k] >> 16], 1);
    }
    __syncthreads();
    if (tid < 64) {   // wave 0: exclusive scan of 256 seg counts (4 per lane)
        int a0 = segcnt[4 * tid], a1 = segcnt[4 * tid + 1];
        int a2 = segcnt[4 * tid + 2], a3 = segcnt[4 * tid + 3];
        int s = a0 + a1 + a2 + a3;
        int inc = s;
        #pragma unroll
        for (int off = 1; off < 64; off <<= 1) {
            int u = __shfl_up(inc, off);
            if (tid >= off) inc += u;
        }
        int excl = inc - s;
        segoff[4 * tid] = excl;
        segoff[4 * tid + 1] = excl + a0;
        segoff[4 * tid + 2] = excl + a0 + a1;
        segoff[4 * tid + 3] = excl + a0 + a1 + a2;
    }
    __syncthreads();
    {
        int seg = (b << 8) + tid;
        if (seg < n2) offs[seg] = lo + segoff[tid];
        segcnt[tid] = segoff[tid];   // running cursors
    }
    if (b == nbuk_eff - 1 && tid == 0) offs[n2] = e2;
    __syncthreads();
    if (count <= BCCAP) {
        for (int k = tid; k < count; k += 256) {
            unsigned st = cache[k];
            int pos = atomicAdd(&segcnt[st >> 16], 1);
            csr[lo + pos] = (int)(st & 0xFFFFu);
        }
    } else {
        for (int k = tid; k < count; k += 256) {
            unsigned st = staging[sbase + k];
            int pos = atomicAdd(&segcnt[st >> 16], 1);
            csr[lo + pos] = (int)(st & 0xFFFFu);
        }
    }
}

// ---------------- gather: ONE wave per node, both directions fused.
// Round-15/16 proven body: 4 acc chains/dir, denominators folded into the
// readlane loop, explicit tail loop (no dummy slots).
__global__ __launch_bounds__(256) void gather_kernel(
    const int* __restrict__ offs, const int* __restrict__ csr,
    const float* __restrict__ s1, const float* __restrict__ d1,
    const float* __restrict__ s2, const float* __restrict__ d2,
    const unsigned short* __restrict__ xw1, const unsigned short* __restrict__ xw2,
    const float* __restrict__ b1, const float* __restrict__ b2,
    float* __restrict__ out, int n)
{
    int i = (blockIdx.x * 256 + threadIdx.x) >> 6;
    int lane = threadIdx.x & 63;
    if (i >= n) return;

    float d1i = d1[i], d2i = d2[i];
    int cF = offs[i],     endF = offs[i + 1];
    int cR = offs[n + i], endR = offs[n + i + 1];

    float pSF = __expf(lrelu(s1[i] + d1i));
    float pSR = __expf(lrelu(s2[i] + d2i));
    float lF0 = pSF, lF1 = 0.f, lR0 = pSR, lR1 = 0.f;
    float aF0 = pSF * bf2f(xw1[(size_t)i * DOUT + lane]), aF1 = 0.f, aF2 = 0.f, aF3 = 0.f;
    float aR0 = pSR * bf2f(xw2[(size_t)i * DOUT + lane]), aR1 = 0.f, aR2 = 0.f, aR3 = 0.f;

    while (cF < endF || cR < endR) {
        int cntF = endF - cF; cntF = cntF < 0 ? 0 : (cntF > 64 ? 64 : cntF);
        int cntR = endR - cR; cntR = cntR < 0 ? 0 : (cntR > 64 ? 64 : cntR);

        int jF = 0, jR = 0;
        float pF = 0.0f, pR = 0.0f;
        if (lane < cntF) { jF = csr[cF + lane]; pF = __expf(lrelu(s1[jF] + d1i)); }
        if (lane < cntR) { jR = csr[cR + lane]; pR = __expf(lrelu(s2[jR] + d2i)); }

        int tmax = cntF > cntR ? cntF : cntR;
        int t = 0;
        for (; t + 4 <= tmax; t += 4) {
            float pF0 = readlane_f(pF, t),     pF1 = readlane_f(pF, t + 1);
            float pF2 = readlane_f(pF, t + 2), pF3 = readlane_f(pF, t + 3);
            int   jF0 = __builtin_amdgcn_readlane(jF, t);
            int   jF1 = __builtin_amdgcn_readlane(jF, t + 1);
            int   jF2 = __builtin_amdgcn_readlane(jF, t + 2);
            int   jF3 = __builtin_amdgcn_readlane(jF, t + 3);
            float pR0 = readlane_f(pR, t),     pR1 = readlane_f(pR, t + 1);
            float pR2 = readlane_f(pR, t + 2), pR3 = readlane_f(pR, t + 3);
            int   jR0 = __builtin_amdgcn_readlane(jR, t);
            int   jR1 = __builtin_amdgcn_readlane(jR, t + 1);
            int   jR2 = __builtin_amdgcn_readlane(jR, t + 2);
            int   jR3 = __builtin_amdgcn_readlane(jR, t + 3);
            lF0 += pF0 + pF1; lF1 += pF2 + pF3;
            lR0 += pR0 + pR1; lR1 += pR2 + pR3;
            aF0 = fmaf(pF0, bf2f(xw1[(size_t)jF0 * DOUT + lane]), aF0);
            aF1 = fmaf(pF1, bf2f(xw1[(size_t)jF1 * DOUT + lane]), aF1);
            aF2 = fmaf(pF2, bf2f(xw1[(size_t)jF2 * DOUT + lane]), aF2);
            aF3 = fmaf(pF3, bf2f(xw1[(size_t)jF3 * DOUT + lane]), aF3);
            aR0 = fmaf(pR0, bf2f(xw2[(size_t)jR0 * DOUT + lane]), aR0);
            aR1 = fmaf(pR1, bf2f(xw2[(size_t)jR1 * DOUT + lane]), aR1);
            aR2 = fmaf(pR2, bf2f(xw2[(size_t)jR2 * DOUT + lane]), aR2);
            aR3 = fmaf(pR3, bf2f(xw2[(size_t)jR3 * DOUT + lane]), aR3);
        }
        for (; t < tmax; ++t) {
            float pF0 = readlane_f(pF, t);
            int   jF0 = __builtin_amdgcn_readlane(jF, t);
            float pR0 = readlane_f(pR, t);
            int   jR0 = __builtin_amdgcn_readlane(jR, t);
            lF0 += pF0; lR0 += pR0;
            aF0 = fmaf(pF0, bf2f(xw1[(size_t)jF0 * DOUT + lane]), aF0);
            aR0 = fmaf(pR0, bf2f(xw2[(size_t)jR0 * DOUT + lane]), aR0);
        }
        cF += cntF;
        cR += cntR;
    }

    float lF = lF0 + lF1, lR = lR0 + lR1;
    float resF = ((aF0 + aF1) + (aF2 + aF3)) / (lF + 1e-16f);
    float resR = ((aR0 + aR1) + (aR2 + aR3)) / (lR + 1e-16f);
    out[(size_t)i * DOUT + lane] =
        (1.0f - ALPHA) * (resF + b1[lane]) + ALPHA * (resR + b2[lane]);
}

extern "C" void kernel_launch(void* const* d_in, const int* in_sizes, int n_in,
                              void* d_out, int out_size, void* d_ws, size_t ws_size,
                              hipStream_t stream) {
    const float* x   = (const float*)d_in[0];
    const int*   ei  = (const int*)d_in[1];
    const float* W1  = (const float*)d_in[2];
    const float* as1 = (const float*)d_in[3];
    const float* ad1 = (const float*)d_in[4];
    const float* b1  = (const float*)d_in[5];
    const float* W2  = (const float*)d_in[6];
    const float* as2 = (const float*)d_in[7];
    const float* ad2 = (const float*)d_in[8];
    const float* b2  = (const float*)d_in[9];
    float* out = (float*)d_out;

    int n = in_sizes[0] / DIN;   // 50000  (< 65536 for 16-bit staging pack)
    int e = in_sizes[1] / 2;     // 800000
    const int* src = ei;
    const int* dst = ei + e;
    int n2 = 2 * n;
    int e2 = 2 * e;
    int nblk = (e + EPB - 1) / EPB;              // 196 edgebin blocks
    int nbuk_eff = (n2 + 255) >> 8;              // 391 non-empty buckets
    int ntiles16 = (n + 15) >> 4;                // 3125 proj tiles
    int projblks = (ntiles16 + 7) / 8;           // 391 proj blocks (8 tiles each)

    // workspace (32-bit words):
    // xw1[32n] xw2[32n] (bf16) s1 d1 s2 d2 [n each] wf[8192]
    // bkcur[NBUK] offs[n2+1] csr[e2] staging[NBUK*CAP]
    unsigned short* xw1 = (unsigned short*)d_ws;
    unsigned short* xw2 = xw1 + (size_t)n * DOUT;
    float* s1  = (float*)(xw2 + (size_t)n * DOUT);
    float* d1  = s1 + n;
    float* s2  = d1 + n;
    float* d2  = s2 + n;
    unsigned short* wf = (unsigned short*)(d2 + n);   // 16384 ushorts = 8192 words
    int* bkcur = (int*)(wf + 16384);
    int* offs  = bkcur + NBUK;
    int* csr   = offs + (size_t)n2 + 1;
    unsigned* staging = (unsigned*)(csr + (size_t)e2);

    hipMemsetAsync(bkcur, 0, NBUK * sizeof(int), stream);

    fusedA_kernel<<<nblk + 8, 256, 0, stream>>>(W1, W2, wf, src, dst,
                                                bkcur, staging, e, n, nblk);

    fusedB_kernel<<<nbuk_eff + projblks, 256, 0, stream>>>(
        bkcur, staging, csr, offs, n2, e2, nbuk_eff,
        x, wf, as1, ad1, as2, ad2, xw1, xw2, s1, d1, s2, d2, n);

    long long gthreads = (long long)n * 64;
    int gblocks = (int)((gthreads + 255) / 256);
    gather_kernel<<<gblocks, 256, 0, stream>>>(offs, csr, s1, d1, s2, d2,
                                               xw1, xw2, b1, b2, out, n);
}